// Round 6
// baseline (179.046 us; speedup 1.0000x reference)
//
#include <hip/hip_runtime.h>
#include <hip/hip_cooperative_groups.h>
#include <hip/hip_fp16.h>
#include <math.h>

namespace cg = cooperative_groups;

#define EE 64
#define HH 128
#define DD 256
#define MHID 512
#define NSC 32
#define PPED 64
#define NTOT 2048
#define MAXP (NTOT * 24)
#define TILE 16
#define NTILES (MAXP / TILE)
#define NGRID 322

typedef __attribute__((ext_vector_type(8))) short short8;
typedef __attribute__((ext_vector_type(4))) float f32x4;
typedef _Float16 half8 __attribute__((ext_vector_type(8)));

// workspace layout
//   floats [0, 2560): A0[512] A1[512] B0[512] B1[512] cvec[512]
//   floats [4096, 4096+1048576): cat[2048][512] (cols 0..255 mx, 256..511 mn)
//   bytes  U16_OFF : U fp16 [2048][512]          (2 MB)
//   bytes  W2T_OFF : Wm2^T bf16 [256][512]       (256 KB)
//   bytes  WPT_OFF : Wp^T  bf16 [256][512]       (256 KB)
//   bytes  PAIR_OFF: uint32 pairs[MAXP]
//   bytes  CNT_OFF : uint32 counter
//   bytes  WM1BT_OFF: Wm1b^T fp16 [512 cols][128 k] (128 KB)
static const int CATF = 4096;
static const size_t U16_OFF = (size_t)(CATF + NTOT * MHID) * 4;
static const size_t W2T_OFF = U16_OFF + (size_t)NTOT * MHID * 2;
static const size_t WPT_OFF = W2T_OFF + (size_t)DD * MHID * 2;
static const size_t PAIR_OFF = WPT_OFF + (size_t)DD * MHID * 2;
static const size_t CNT_OFF = PAIR_OFF + (size_t)MAXP * 4;
static const size_t WM1BT_OFF = CNT_OFF + 16;

__device__ __forceinline__ unsigned short f2bf(float f) {
  unsigned int u = __float_as_uint(f);
  return (unsigned short)((u + 0x7fffu + ((u >> 16) & 1u)) >> 16);
}
__device__ __forceinline__ unsigned short f2h(float f) {
  return __half_as_ushort(__float2half(f));
}

// ================= phase A: cat-init + cnt + coeff fold + transposes =============
__device__ void phaseA(int b, int tid, const float* __restrict__ Ws,
                       const float* __restrict__ bs, const float* __restrict__ Wv,
                       const float* __restrict__ bv, const float* __restrict__ Wm1,
                       const float* __restrict__ bm1, const float* __restrict__ Wm2,
                       const float* __restrict__ Wp, float* __restrict__ ws,
                       unsigned short* Tsh) {
  if (b < 256) {
    if (b == 0 && tid == 0) *((unsigned int*)((char*)ws + CNT_OFF)) = 0u;
    float inf = __uint_as_float(0x7f800000u);
    float4 iv = make_float4(inf, inf, inf, inf);
    float4 zv = make_float4(0.f, 0.f, 0.f, 0.f);
    float4* cat4 = (float4*)(ws + CATF);
    int t = b * 256 + tid;
#pragma unroll
    for (int s = 0; s < 4; ++s) {
      int f4 = t + s * 65536;
      int col = (f4 * 4) & 511;
      cat4[f4] = (col & 256) ? iv : zv;
    }
  } else if (b < 258) {
    int m = (b - 256) * 256 + tid;
    float a0 = 0.f, a1 = 0.f, b0 = 0.f, b1 = 0.f, cs = 0.f, cv = 0.f;
    for (int e = 0; e < EE; ++e) {
      float w1 = Wm1[e * MHID + m];
      float w2 = Wm1[(EE + e) * MHID + m];
      a0 = fmaf(Ws[e], w1, a0);
      a1 = fmaf(Ws[EE + e], w1, a1);
      b0 = fmaf(Wv[e], w2, b0);
      b1 = fmaf(Wv[EE + e], w2, b1);
      cs = fmaf(bs[e], w1, cs);
      cv = fmaf(bv[e], w2, cv);
    }
    ws[m] = a0;
    ws[MHID + m] = a1;
    ws[2 * MHID + m] = b0;
    ws[3 * MHID + m] = b1;
    ws[4 * MHID + m] = bm1[m] + cs + cv;
  } else if (b < 290) {
    const float* src = (b < 274) ? Wm2 : Wp;
    unsigned short* dst = (unsigned short*)((char*)ws + ((b < 274) ? W2T_OFF : WPT_OFF));
    int c0 = ((b < 274) ? (b - 258) : (b - 274)) * 16;
#pragma unroll 4
    for (int it = 0; it < 32; ++it) {
      int k = it * 16 + (tid >> 4);
      int c = tid & 15;
      Tsh[c * MHID + k] = f2bf(src[(size_t)k * DD + c0 + c]);
    }
    __syncthreads();
    unsigned int* dst32 = (unsigned int*)dst;
#pragma unroll 4
    for (int it = 0; it < 16; ++it) {
      int flat = it * 256 + tid;
      int c = flat >> 8;
      int ku = flat & 255;
      unsigned int lo = Tsh[c * MHID + 2 * ku];
      unsigned int hi = Tsh[c * MHID + 2 * ku + 1];
      dst32[(size_t)(c0 + c) * (MHID / 2) + ku] = lo | (hi << 16);
    }
  } else {
    unsigned short* dst = (unsigned short*)((char*)ws + WM1BT_OFF);
    int c0 = (b - 290) * 16;
#pragma unroll
    for (int it = 0; it < 8; ++it) {
      int k = it * 16 + (tid >> 4);
      int c = tid & 15;
      Tsh[c * HH + k] = f2h(Wm1[(size_t)(2 * EE + k) * MHID + c0 + c]);
    }
    __syncthreads();
    unsigned int* dst32 = (unsigned int*)dst;
#pragma unroll
    for (int it = 0; it < 4; ++it) {
      int flat = it * 256 + tid;
      int c = flat >> 6;
      int ku = flat & 63;
      unsigned int lo = Tsh[c * HH + 2 * ku];
      unsigned int hi = Tsh[c * HH + 2 * ku + 1];
      dst32[(size_t)(c0 + c) * (HH / 2) + ku] = lo | (hi << 16);
    }
  }
}

// ================= phase B: U via MFMA f16 + visibility mask ====================
__device__ void phaseB(int b, int tid, const float* __restrict__ hstates,
                       const float* __restrict__ pos, const float* __restrict__ vel,
                       const float* __restrict__ bpos, float* __restrict__ ws,
                       unsigned int* __restrict__ pairs, unsigned int* __restrict__ cnt,
                       char* raw) {
  if (b < 256) {
    unsigned short* Ash = (unsigned short*)raw;
    const unsigned short* wm1bt = (const unsigned short*)((const char*)ws + WM1BT_OFF);
    unsigned short* u16 = (unsigned short*)((char*)ws + U16_OFF);
    int bx = b >> 2, by = b & 3;
    int n0 = bx * 32, C0 = by * 128;
    {
      int p = tid >> 3, kq = (tid & 7) * 16;
      const float* hp = hstates + (size_t)(n0 + p) * HH + kq;
      float4 f0 = *(const float4*)(hp);
      float4 f1 = *(const float4*)(hp + 4);
      float4 f2 = *(const float4*)(hp + 8);
      float4 f3 = *(const float4*)(hp + 12);
      int swz = (p & 7) << 3;
      uint4 v0, v1;
      v0.x = f2h(f0.x) | ((unsigned int)f2h(f0.y) << 16);
      v0.y = f2h(f0.z) | ((unsigned int)f2h(f0.w) << 16);
      v0.z = f2h(f1.x) | ((unsigned int)f2h(f1.y) << 16);
      v0.w = f2h(f1.z) | ((unsigned int)f2h(f1.w) << 16);
      v1.x = f2h(f2.x) | ((unsigned int)f2h(f2.y) << 16);
      v1.y = f2h(f2.z) | ((unsigned int)f2h(f2.w) << 16);
      v1.z = f2h(f3.x) | ((unsigned int)f2h(f3.y) << 16);
      v1.w = f2h(f3.z) | ((unsigned int)f2h(f3.w) << 16);
      *(uint4*)(Ash + ((p * HH + kq) ^ swz)) = v0;
      *(uint4*)(Ash + ((p * HH + kq + 8) ^ swz)) = v1;
    }
    __syncthreads();
    int w = tid >> 6, l = tid & 63;
    int lr = l & 15, lg = l >> 4;
    f32x4 acc[2][2];
#pragma unroll
    for (int i = 0; i < 2; ++i)
#pragma unroll
      for (int j = 0; j < 2; ++j) acc[i][j] = (f32x4){0.f, 0.f, 0.f, 0.f};
    int aswz = (lr & 7) << 3;
#pragma unroll
    for (int ks = 0; ks < 4; ++ks) {
      int k0 = ks * 32 + lg * 8;
      half8 a0 = *(const half8*)(Ash + ((lr * HH + k0) ^ aswz));
      half8 a1 = *(const half8*)(Ash + (((16 + lr) * HH + k0) ^ aswz));
      const unsigned short* bb = wm1bt + (size_t)(C0 + w * 32 + lr) * HH + k0;
      half8 b0 = *(const half8*)(bb);
      half8 b1 = *(const half8*)(bb + 16 * HH);
      acc[0][0] = __builtin_amdgcn_mfma_f32_16x16x32_f16(a0, b0, acc[0][0], 0, 0, 0);
      acc[0][1] = __builtin_amdgcn_mfma_f32_16x16x32_f16(a0, b1, acc[0][1], 0, 0, 0);
      acc[1][0] = __builtin_amdgcn_mfma_f32_16x16x32_f16(a1, b0, acc[1][0], 0, 0, 0);
      acc[1][1] = __builtin_amdgcn_mfma_f32_16x16x32_f16(a1, b1, acc[1][1], 0, 0, 0);
    }
#pragma unroll
    for (int ct = 0; ct < 2; ++ct) {
      int col = C0 + w * 32 + ct * 16 + lr;
      float a0c = ws[col], a1c = ws[MHID + col], b0c = ws[2 * MHID + col],
            b1c = ws[3 * MHID + col], cc = ws[4 * MHID + col];
#pragma unroll
      for (int rt = 0; rt < 2; ++rt) {
#pragma unroll
        for (int r = 0; r < 4; ++r) {
          int row = n0 + rt * 16 + lg * 4 + r;
          float px = pos[row * 2], py = pos[row * 2 + 1];
          float vx = vel[row * 2], vy = vel[row * 2 + 1];
          float uv = acc[rt][ct][r] + px * a0c + py * a1c + vx * b0c + vy * b1c + cc;
          u16[(size_t)row * MHID + col] = f2h(uv);
        }
      }
    }
  } else if (b < 288) {
    double* sx = (double*)raw;
    double* sy = sx + PPED;
    int scene = b - 256;
    int i = tid;
    double px = 0.0, py = 0.0, xb = 0.0, yb = 0.0;
    int n = scene * PPED + i;
    if (tid < PPED) {
      px = (double)pos[n * 2];
      py = (double)pos[n * 2 + 1];
      sx[i] = px;
      sy[i] = py;
      xb = (double)bpos[n * 2];
      yb = (double)bpos[n * 2 + 1];
    }
    __syncthreads();
    if (tid < PPED) {
      double xr = px - xb, yr = py - yb;
      double safe = (xr == 0.0) ? 1.0 : fabs(xr);
      double at = atan(fabs(yr) / safe);
      const double r90 = M_PI / 2.0, r180 = M_PI, r270 = 3.0 * M_PI / 2.0;
      double ang;
      if (xr > 0.0 && yr > 0.0) ang = at + r270;
      else if (xr < 0.0 && yr > 0.0) ang = r90 - at;
      else if (xr < 0.0 && yr < 0.0) ang = r90 + at;
      else if (xr > 0.0 && yr < 0.0) ang = r270 - at;
      else if (xr == 0.0 && yr > 0.0) ang = 0.0;
      else if (xr == 0.0 && yr < 0.0) ang = r180;
      else if (yr == 0.0 && xr > 0.0) ang = r270;
      else if (yr == 0.0 && xr < 0.0) ang = r90;
      else ang = 0.0;
      double cd = cos(ang), sd = sin(ang);
      const double cc2 = 2.0 / cos(60.0 * M_PI / 180.0);
      const double bb = sin(60.0 * M_PI / 180.0) * cc2;  // 2*sqrt(3)
      unsigned long long mw = 0ull;
      for (int j = 0; j < PPED; ++j) {
        if (j == i) continue;
        double dx = sx[j] - px, dy = sy[j] - py;
        double xt = cd * dx - sd * dy;
        double yt = sd * dx + cd * dy;
        double res = (yt >= 0.0) ? (xt * xt + yt * yt / 4.0) : (xt * xt + yt * yt);
        bool egg = (res <= 1.0);
        double c1 = 2.0 * xt + bb * yt;
        double c2 = 2.0 * xt - bb * yt;
        bool cone = (c1 > 0.0 && c2 < 0.0) || (c1 == 0.0) || (c2 == 0.0);
        if (egg && (yt >= 0.0) && cone) mw |= (1ull << j);
      }
      int c = __popcll(mw);
      if (c > 0) {
        unsigned int base = atomicAdd(cnt, (unsigned int)c);
        if (base < (unsigned int)MAXP) {
          int lim = MAXP - (int)base;
          if (lim > c) lim = c;
          unsigned long long rem = mw;
          unsigned int hi = ((unsigned int)n) << 16;
          for (int q = 0; q < lim; ++q) {
            int j = __builtin_ctzll(rem);
            rem &= rem - 1;
            pairs[base + q] = hi | (unsigned int)(scene * PPED + j);
          }
        }
      }
    }
  }
}

// ================= phase C: one pair-tile (MFMA layer2 + run-scan pool) ==========
__device__ void phaseC_tile(int t0, int np, int tid, const float* __restrict__ ws,
                            const unsigned int* __restrict__ pairs,
                            const float* __restrict__ pos, const float* __restrict__ vel,
                            const float* __restrict__ bm2, float* __restrict__ cat,
                            float* smem, int* si, int* sjj, float (*spv)[4]) {
  unsigned short* Ash = (unsigned short*)smem;
  const unsigned short* u16 = (const unsigned short*)((const char*)ws + U16_OFF);
  const short* w2t = (const short*)((const char*)ws + W2T_OFF);
  if (tid < TILE) {
    int p = t0 + tid;
    unsigned int pk = (p < np) ? pairs[p] : pairs[t0];
    int ii = (int)(pk >> 16), jj = (int)(pk & 0xFFFFu);
    si[tid] = ii;
    sjj[tid] = jj;
    spv[tid][0] = pos[ii * 2];
    spv[tid][1] = pos[ii * 2 + 1];
    spv[tid][2] = vel[ii * 2];
    spv[tid][3] = vel[ii * 2 + 1];
  }
  __syncthreads();
  {
    int pr = tid & 15, seg = tid >> 4;
    int jj = sjj[pr];
    float px = spv[pr][0], py = spv[pr][1], vx = spv[pr][2], vy = spv[pr][3];
    const unsigned short* Up = u16 + (size_t)jj * MHID + seg * 32;
    int swz = (pr & 7) << 3;
#pragma unroll
    for (int q = 0; q < 4; ++q) {
      int k0 = seg * 32 + q * 8;
      uint4 uv = *(const uint4*)(Up + q * 8);
      float4 c0a = *(const float4*)(ws + k0);
      float4 c0b = *(const float4*)(ws + k0 + 4);
      float4 c1a = *(const float4*)(ws + MHID + k0);
      float4 c1b = *(const float4*)(ws + MHID + k0 + 4);
      float4 c2a = *(const float4*)(ws + 2 * MHID + k0);
      float4 c2b = *(const float4*)(ws + 2 * MHID + k0 + 4);
      float4 c3a = *(const float4*)(ws + 3 * MHID + k0);
      float4 c3b = *(const float4*)(ws + 3 * MHID + k0 + 4);
      float u0 = __half2float(__ushort_as_half((unsigned short)(uv.x & 0xffff)));
      float u1 = __half2float(__ushort_as_half((unsigned short)(uv.x >> 16)));
      float u2 = __half2float(__ushort_as_half((unsigned short)(uv.y & 0xffff)));
      float u3 = __half2float(__ushort_as_half((unsigned short)(uv.y >> 16)));
      float u4 = __half2float(__ushort_as_half((unsigned short)(uv.z & 0xffff)));
      float u5 = __half2float(__ushort_as_half((unsigned short)(uv.z >> 16)));
      float u6 = __half2float(__ushort_as_half((unsigned short)(uv.w & 0xffff)));
      float u7 = __half2float(__ushort_as_half((unsigned short)(uv.w >> 16)));
      unsigned int h0 =
          f2bf(fmaxf(u0 - (px * c0a.x + py * c1a.x + vx * c2a.x + vy * c3a.x), 0.f));
      unsigned int h1 =
          f2bf(fmaxf(u1 - (px * c0a.y + py * c1a.y + vx * c2a.y + vy * c3a.y), 0.f));
      unsigned int h2 =
          f2bf(fmaxf(u2 - (px * c0a.z + py * c1a.z + vx * c2a.z + vy * c3a.z), 0.f));
      unsigned int h3 =
          f2bf(fmaxf(u3 - (px * c0a.w + py * c1a.w + vx * c2a.w + vy * c3a.w), 0.f));
      unsigned int h4 =
          f2bf(fmaxf(u4 - (px * c0b.x + py * c1b.x + vx * c2b.x + vy * c3b.x), 0.f));
      unsigned int h5 =
          f2bf(fmaxf(u5 - (px * c0b.y + py * c1b.y + vx * c2b.y + vy * c3b.y), 0.f));
      unsigned int h6 =
          f2bf(fmaxf(u6 - (px * c0b.z + py * c1b.z + vx * c2b.z + vy * c3b.z), 0.f));
      unsigned int h7 =
          f2bf(fmaxf(u7 - (px * c0b.w + py * c1b.w + vx * c2b.w + vy * c3b.w), 0.f));
      uint4 pk4;
      pk4.x = h0 | (h1 << 16);
      pk4.y = h2 | (h3 << 16);
      pk4.z = h4 | (h5 << 16);
      pk4.w = h6 | (h7 << 16);
      *(uint4*)(Ash + (((pr * MHID + k0)) ^ swz)) = pk4;
    }
  }
  __syncthreads();
  int w = tid >> 6, l = tid & 63;
  f32x4 acc0 = {0.f, 0.f, 0.f, 0.f}, acc1 = {0.f, 0.f, 0.f, 0.f};
  f32x4 acc2 = {0.f, 0.f, 0.f, 0.f}, acc3 = {0.f, 0.f, 0.f, 0.f};
  int arow = l & 15, agrp = l >> 4;
  int aswz = (arow & 7) << 3;
#pragma unroll 4
  for (int ks = 0; ks < 16; ++ks) {
    short8 a = *(const short8*)(Ash + ((arow * MHID + ks * 32 + agrp * 8) ^ aswz));
    const short* bbase = w2t + (size_t)(w * 4 * 16 + (l & 15)) * MHID + ks * 32 + agrp * 8;
    short8 b0 = *(const short8*)(bbase);
    short8 b1 = *(const short8*)(bbase + 16 * MHID);
    short8 b2 = *(const short8*)(bbase + 32 * MHID);
    short8 b3 = *(const short8*)(bbase + 48 * MHID);
    acc0 = __builtin_amdgcn_mfma_f32_16x16x32_bf16(a, b0, acc0, 0, 0, 0);
    acc1 = __builtin_amdgcn_mfma_f32_16x16x32_bf16(a, b1, acc1, 0, 0, 0);
    acc2 = __builtin_amdgcn_mfma_f32_16x16x32_bf16(a, b2, acc2, 0, 0, 0);
    acc3 = __builtin_amdgcn_mfma_f32_16x16x32_bf16(a, b3, acc3, 0, 0, 0);
  }
  __syncthreads();
  {
#pragma unroll
    for (int t = 0; t < 4; ++t) {
      int col = (w * 4 + t) * 16 + (l & 15);
      float bias = bm2[col];
      f32x4 av = (t == 0) ? acc0 : (t == 1) ? acc1 : (t == 2) ? acc2 : acc3;
#pragma unroll
      for (int r = 0; r < 4; ++r) {
        int row = (l >> 4) * 4 + r;
        smem[row * DD + col] = fmaxf(av[r] + bias, 0.f);
      }
    }
  }
  __syncthreads();
  int col = tid;
  int lastv = np - t0;
  if (lastv > TILE) lastv = TILE;
  float rmx = 0.f, rmn = 0.f;
  int cur = -1, rs = 0;
  for (int r = 0; r < lastv; ++r) {
    int ii = si[r];
    float v = smem[r * DD + col];
    if (ii != cur) {
      if (cur >= 0) {
        bool shared_run = (rs == 0 && t0 > 0);
        float* mp = cat + (size_t)cur * 2 * DD + col;
        if (shared_run) {
          atomicMax((unsigned int*)mp, __float_as_uint(rmx));
          atomicMin((unsigned int*)(mp + DD), __float_as_uint(rmn));
        } else {
          mp[0] = rmx;
          mp[DD] = rmn;
        }
      }
      cur = ii;
      rs = r;
      rmx = v;
      rmn = v;
    } else {
      rmx = fmaxf(rmx, v);
      rmn = fminf(rmn, v);
    }
  }
  if (cur >= 0) {
    bool shared_run = (rs == 0 && t0 > 0) || ((lastv == TILE) && (t0 + TILE) < np);
    float* mp = cat + (size_t)cur * 2 * DD + col;
    if (shared_run) {
      atomicMax((unsigned int*)mp, __float_as_uint(rmx));
      atomicMin((unsigned int*)(mp + DD), __float_as_uint(rmn));
    } else {
      mp[0] = rmx;
      mp[DD] = rmn;
    }
  }
}

// ================= phase D: out = relu(cat @ Wp + bp) via MFMA ==================
__device__ void phaseD(int b, int tid, const float* __restrict__ ws,
                       const float* __restrict__ bp, float* __restrict__ out) {
  const float* cat = ws + CATF;
  const short* wpt = (const short*)((const char*)ws + WPT_OFF);
  int m0 = b * 16;
  int w = tid >> 6, l = tid & 63;
  int arow = m0 + (l & 15), agrp = l >> 4;
  f32x4 acc0 = {0.f, 0.f, 0.f, 0.f}, acc1 = {0.f, 0.f, 0.f, 0.f};
  f32x4 acc2 = {0.f, 0.f, 0.f, 0.f}, acc3 = {0.f, 0.f, 0.f, 0.f};
#pragma unroll 4
  for (int ks = 0; ks < 16; ++ks) {
    const float* ap = cat + (size_t)arow * MHID + ks * 32 + agrp * 8;
    float4 fa = *(const float4*)(ap);
    float4 fb = *(const float4*)(ap + 4);
    unsigned int e0 = __float_as_uint(fa.x), e1 = __float_as_uint(fa.y);
    unsigned int e2 = __float_as_uint(fa.z), e3 = __float_as_uint(fa.w);
    unsigned int e4 = __float_as_uint(fb.x), e5 = __float_as_uint(fb.y);
    unsigned int e6 = __float_as_uint(fb.z), e7 = __float_as_uint(fb.w);
    unsigned int h0 = (e0 == 0x7f800000u) ? 0u : (unsigned int)f2bf(fa.x);
    unsigned int h1 = (e1 == 0x7f800000u) ? 0u : (unsigned int)f2bf(fa.y);
    unsigned int h2 = (e2 == 0x7f800000u) ? 0u : (unsigned int)f2bf(fa.z);
    unsigned int h3 = (e3 == 0x7f800000u) ? 0u : (unsigned int)f2bf(fa.w);
    unsigned int h4 = (e4 == 0x7f800000u) ? 0u : (unsigned int)f2bf(fb.x);
    unsigned int h5 = (e5 == 0x7f800000u) ? 0u : (unsigned int)f2bf(fb.y);
    unsigned int h6 = (e6 == 0x7f800000u) ? 0u : (unsigned int)f2bf(fb.z);
    unsigned int h7 = (e7 == 0x7f800000u) ? 0u : (unsigned int)f2bf(fb.w);
    union {
      unsigned int u[4];
      short8 s;
    } av;
    av.u[0] = h0 | (h1 << 16);
    av.u[1] = h2 | (h3 << 16);
    av.u[2] = h4 | (h5 << 16);
    av.u[3] = h6 | (h7 << 16);
    const short* bbase = wpt + (size_t)(w * 64 + (l & 15)) * MHID + ks * 32 + agrp * 8;
    short8 b0 = *(const short8*)(bbase);
    short8 b1 = *(const short8*)(bbase + 16 * MHID);
    short8 b2 = *(const short8*)(bbase + 32 * MHID);
    short8 b3 = *(const short8*)(bbase + 48 * MHID);
    acc0 = __builtin_amdgcn_mfma_f32_16x16x32_bf16(av.s, b0, acc0, 0, 0, 0);
    acc1 = __builtin_amdgcn_mfma_f32_16x16x32_bf16(av.s, b1, acc1, 0, 0, 0);
    acc2 = __builtin_amdgcn_mfma_f32_16x16x32_bf16(av.s, b2, acc2, 0, 0, 0);
    acc3 = __builtin_amdgcn_mfma_f32_16x16x32_bf16(av.s, b3, acc3, 0, 0, 0);
  }
#pragma unroll
  for (int t = 0; t < 4; ++t) {
    int col = (w * 4 + t) * 16 + (l & 15);
    float bias = bp[col];
    f32x4 av = (t == 0) ? acc0 : (t == 1) ? acc1 : (t == 2) ? acc2 : acc3;
#pragma unroll
    for (int r = 0; r < 4; ++r) {
      int row = m0 + (l >> 4) * 4 + r;
      out[(size_t)row * DD + col] = fmaxf(av[r] + bias, 0.f);
    }
  }
}

// ================= fused cooperative kernel ==================
__global__ __launch_bounds__(256, 2) void k_all(
    const float* __restrict__ hstates, const float* __restrict__ pos,
    const float* __restrict__ vel, const float* __restrict__ bpos,
    const float* __restrict__ Ws, const float* __restrict__ bs,
    const float* __restrict__ Wv, const float* __restrict__ bv,
    const float* __restrict__ Wm1, const float* __restrict__ bm1,
    const float* __restrict__ Wm2, const float* __restrict__ bm2,
    const float* __restrict__ Wp, const float* __restrict__ bp,
    float* __restrict__ ws, float* __restrict__ out) {
  __shared__ __align__(16) char smem[16896];
  __shared__ int si[TILE], sjj[TILE];
  __shared__ float spv[TILE][4];
  int b = blockIdx.x, tid = threadIdx.x;
  unsigned int* pairs = (unsigned int*)((char*)ws + PAIR_OFF);
  unsigned int* cnt = (unsigned int*)((char*)ws + CNT_OFF);
  phaseA(b, tid, Ws, bs, Wv, bv, Wm1, bm1, Wm2, Wp, ws, (unsigned short*)smem);
  cg::this_grid().sync();
  phaseB(b, tid, hstates, pos, vel, bpos, ws, pairs, cnt, smem);
  cg::this_grid().sync();
  int np = (int)__hip_atomic_load(cnt, __ATOMIC_ACQUIRE, __HIP_MEMORY_SCOPE_AGENT);
  if (np > MAXP) np = MAXP;
  for (int t = b; t * TILE < np; t += NGRID) {
    __syncthreads();
    phaseC_tile(t * TILE, np, tid, ws, pairs, pos, vel, bm2, ws + CATF, (float*)smem, si,
                sjj, spv);
  }
  cg::this_grid().sync();
  if (b < NTOT / 16) phaseD(b, tid, ws, bp, out);
}

// ================= fallback separate kernels (if cooperative launch fails) ======
__global__ __launch_bounds__(256) void k_prep(
    const float* __restrict__ Ws, const float* __restrict__ bs,
    const float* __restrict__ Wv, const float* __restrict__ bv,
    const float* __restrict__ Wm1, const float* __restrict__ bm1,
    const float* __restrict__ Wm2, const float* __restrict__ Wp,
    float* __restrict__ ws) {
  __shared__ __align__(16) char smem[16896];
  phaseA(blockIdx.x, threadIdx.x, Ws, bs, Wv, bv, Wm1, bm1, Wm2, Wp, ws,
         (unsigned short*)smem);
}

__global__ __launch_bounds__(256) void k1m(
    const float* __restrict__ hstates, const float* __restrict__ pos,
    const float* __restrict__ vel, const float* __restrict__ bpos,
    float* __restrict__ ws, unsigned int* __restrict__ pairs,
    unsigned int* __restrict__ cnt) {
  __shared__ __align__(16) char smem[16896];
  phaseB(blockIdx.x, threadIdx.x, hstates, pos, vel, bpos, ws, pairs, cnt, smem);
}

__global__ __launch_bounds__(256) void k3m(
    const float* __restrict__ ws, const unsigned int* __restrict__ pairs,
    const unsigned int* __restrict__ cnt, const float* __restrict__ pos,
    const float* __restrict__ vel, const float* __restrict__ bm2,
    float* __restrict__ cat) {
  __shared__ __align__(16) char smem[16896];
  __shared__ int si[TILE], sjj[TILE];
  __shared__ float spv[TILE][4];
  int np = (int)*cnt;
  if (np > MAXP) np = MAXP;
  int t0 = blockIdx.x * TILE;
  if (t0 >= np) return;
  phaseC_tile(t0, np, threadIdx.x, ws, pairs, pos, vel, bm2, cat, (float*)smem, si, sjj,
              spv);
}

__global__ __launch_bounds__(256) void k4m(const float* __restrict__ ws,
                                           const float* __restrict__ bp,
                                           float* __restrict__ out) {
  phaseD(blockIdx.x, threadIdx.x, ws, bp, out);
}

extern "C" void kernel_launch(void* const* d_in, const int* in_sizes, int n_in,
                              void* d_out, int out_size, void* d_ws, size_t ws_size,
                              hipStream_t stream) {
  const float* hstates = (const float*)d_in[0];
  const float* pos = (const float*)d_in[2];
  const float* vel = (const float*)d_in[3];
  const float* bpos = (const float*)d_in[4];
  const float* Ws = (const float*)d_in[5];
  const float* bs = (const float*)d_in[6];
  const float* Wv = (const float*)d_in[7];
  const float* bv = (const float*)d_in[8];
  const float* Wm1 = (const float*)d_in[9];
  const float* bm1 = (const float*)d_in[10];
  const float* Wm2 = (const float*)d_in[11];
  const float* bm2 = (const float*)d_in[12];
  const float* Wp = (const float*)d_in[13];
  const float* bp = (const float*)d_in[14];
  float* ws = (float*)d_ws;
  float* out = (float*)d_out;
  unsigned int* pairs = (unsigned int*)((char*)d_ws + PAIR_OFF);
  unsigned int* cntp = (unsigned int*)((char*)d_ws + CNT_OFF);

  void* kargs[16] = {(void*)&hstates, (void*)&pos, (void*)&vel, (void*)&bpos,
                     (void*)&Ws,      (void*)&bs,  (void*)&Wv,  (void*)&bv,
                     (void*)&Wm1,     (void*)&bm1, (void*)&Wm2, (void*)&bm2,
                     (void*)&Wp,      (void*)&bp,  (void*)&ws,  (void*)&out};
  hipError_t err = hipLaunchCooperativeKernel((const void*)k_all, dim3(NGRID), dim3(256),
                                              kargs, 0u, stream);
  if (err != hipSuccess) {
    // fallback: proven 4-launch pipeline
    hipLaunchKernelGGL(k_prep, dim3(NGRID), dim3(256), 0, stream, Ws, bs, Wv, bv, Wm1,
                       bm1, Wm2, Wp, ws);
    hipLaunchKernelGGL(k1m, dim3(288), dim3(256), 0, stream, hstates, pos, vel, bpos, ws,
                       pairs, cntp);
    hipLaunchKernelGGL(k3m, dim3(NTILES), dim3(256), 0, stream, ws, pairs, cntp, pos, vel,
                       bm2, ws + CATF);
    hipLaunchKernelGGL(k4m, dim3(NTOT / 16), dim3(256), 0, stream, ws, bp, out);
  }
}

// Round 7
// 73.644 us; speedup vs baseline: 2.4312x; 2.4312x over previous
//
#include <hip/hip_runtime.h>
#include <hip/hip_fp16.h>
#include <math.h>

#define EE 64
#define HH 128
#define DD 256
#define MHID 512
#define NSC 32
#define PPED 64
#define NTOT 2048
#define TILE 16
#define PPS 1024   // pairs per scene cap (mean ~110)
#define MAXT (PPS / TILE)

typedef __attribute__((ext_vector_type(8))) short short8;
typedef __attribute__((ext_vector_type(4))) float f32x4;
typedef _Float16 half8 __attribute__((ext_vector_type(8)));

// workspace layout
//   floats [0, 2560): A0[512] A1[512] B0[512] B1[512] cvec[512]
//   floats [4096, 4096+1048576): cat[2048][512] (cols 0..255 mx, 256..511 mn)
//   bytes  U16_OFF : U_hid fp16 [2048][512]      (2 MB)
//   bytes  W2T_OFF : Wm2^T bf16 [256][512]       (256 KB)
//   bytes  WPT_OFF : Wp^T  bf16 [256][512]       (256 KB)
//   bytes  PAIR_OFF: uint32 pairs[32][1024]
//   bytes  SCNT_OFF: uint32 scnt[32]
static const int CATF = 4096;
static const size_t U16_OFF = (size_t)(CATF + NTOT * MHID) * 4;
static const size_t W2T_OFF = U16_OFF + (size_t)NTOT * MHID * 2;
static const size_t WPT_OFF = W2T_OFF + (size_t)DD * MHID * 2;
static const size_t PAIR_OFF = WPT_OFF + (size_t)DD * MHID * 2;
static const size_t SCNT_OFF = PAIR_OFF + (size_t)NSC * PPS * 4;

__device__ __forceinline__ unsigned short f2bf(float f) {
  unsigned int u = __float_as_uint(f);
  return (unsigned short)((u + 0x7fffu + ((u >> 16) & 1u)) >> 16);
}
__device__ __forceinline__ unsigned short f2h(float f) {
  return __half_as_ushort(__float2half(f));
}

// ============ kB: U-hid GEMM + masks + cat-init + coeffs + transposes ============
// blocks [0,256): U-hid GEMM     [256,288): scene masks  [288,544): cat-init
// [544,546): coeff fold          [546,562): Wm2^T        [562,578): Wp^T
__global__ __launch_bounds__(256) void kB(
    const float* __restrict__ hstates, const float* __restrict__ pos,
    const float* __restrict__ vel, const float* __restrict__ bpos,
    const float* __restrict__ Ws, const float* __restrict__ bs,
    const float* __restrict__ Wv, const float* __restrict__ bv,
    const float* __restrict__ Wm1, const float* __restrict__ bm1,
    const float* __restrict__ Wm2, const float* __restrict__ Wp,
    float* __restrict__ ws) {
  __shared__ __align__(16) char smem[16896];
  int b = blockIdx.x, tid = threadIdx.x;
  if (b < 256) {
    // ---- U_hid = hid @ Wm1b via MFMA f16 ----
    unsigned short* Ash = (unsigned short*)smem;
    unsigned short* u16 = (unsigned short*)((char*)ws + U16_OFF);
    int bx = b >> 2, by = b & 3;
    int n0 = bx * 32, C0 = by * 128;
    {
      int p = tid >> 3, kq = (tid & 7) * 16;
      const float* hp = hstates + (size_t)(n0 + p) * HH + kq;
      float4 f0 = *(const float4*)(hp);
      float4 f1 = *(const float4*)(hp + 4);
      float4 f2 = *(const float4*)(hp + 8);
      float4 f3 = *(const float4*)(hp + 12);
      int swz = (p & 7) << 3;
      uint4 v0, v1;
      v0.x = f2h(f0.x) | ((unsigned int)f2h(f0.y) << 16);
      v0.y = f2h(f0.z) | ((unsigned int)f2h(f0.w) << 16);
      v0.z = f2h(f1.x) | ((unsigned int)f2h(f1.y) << 16);
      v0.w = f2h(f1.z) | ((unsigned int)f2h(f1.w) << 16);
      v1.x = f2h(f2.x) | ((unsigned int)f2h(f2.y) << 16);
      v1.y = f2h(f2.z) | ((unsigned int)f2h(f2.w) << 16);
      v1.z = f2h(f3.x) | ((unsigned int)f2h(f3.y) << 16);
      v1.w = f2h(f3.z) | ((unsigned int)f2h(f3.w) << 16);
      *(uint4*)(Ash + ((p * HH + kq) ^ swz)) = v0;
      *(uint4*)(Ash + ((p * HH + kq + 8) ^ swz)) = v1;
    }
    __syncthreads();
    int w = tid >> 6, l = tid & 63;
    int lr = l & 15, lg = l >> 4;
    f32x4 acc[2][2];
#pragma unroll
    for (int i = 0; i < 2; ++i)
#pragma unroll
      for (int j = 0; j < 2; ++j) acc[i][j] = (f32x4){0.f, 0.f, 0.f, 0.f};
    int aswz = (lr & 7) << 3;
    int col0 = C0 + w * 32 + lr;
#pragma unroll
    for (int ks = 0; ks < 4; ++ks) {
      int k0 = ks * 32 + lg * 8;
      half8 a0 = *(const half8*)(Ash + ((lr * HH + k0) ^ aswz));
      half8 a1 = *(const half8*)(Ash + (((16 + lr) * HH + k0) ^ aswz));
      half8 b0, b1;
#pragma unroll
      for (int q = 0; q < 8; ++q) {
        b0[q] = (_Float16)Wm1[(size_t)(2 * EE + k0 + q) * MHID + col0];
        b1[q] = (_Float16)Wm1[(size_t)(2 * EE + k0 + q) * MHID + col0 + 16];
      }
      acc[0][0] = __builtin_amdgcn_mfma_f32_16x16x32_f16(a0, b0, acc[0][0], 0, 0, 0);
      acc[0][1] = __builtin_amdgcn_mfma_f32_16x16x32_f16(a0, b1, acc[0][1], 0, 0, 0);
      acc[1][0] = __builtin_amdgcn_mfma_f32_16x16x32_f16(a1, b0, acc[1][0], 0, 0, 0);
      acc[1][1] = __builtin_amdgcn_mfma_f32_16x16x32_f16(a1, b1, acc[1][1], 0, 0, 0);
    }
#pragma unroll
    for (int ct = 0; ct < 2; ++ct) {
      int col = C0 + w * 32 + ct * 16 + lr;
#pragma unroll
      for (int rt = 0; rt < 2; ++rt) {
#pragma unroll
        for (int r = 0; r < 4; ++r) {
          int row = n0 + rt * 16 + lg * 4 + r;
          u16[(size_t)row * MHID + col] = f2h(acc[rt][ct][r]);
        }
      }
    }
  } else if (b < 288) {
    // ---- visibility mask, per-scene compaction (no global atomics) ----
    double* sx = (double*)smem;
    double* sy = (double*)(smem + 512);
    int* cnt_sh = (int*)(smem + 1024);
    int* pref_sh = (int*)(smem + 1280);
    unsigned long long* mw_sh = (unsigned long long*)(smem + 1544);
    int scene = b - 256;
    int i = tid;
    int n = scene * PPED + i;
    double px = 0.0, py = 0.0, xb = 0.0, yb = 0.0;
    if (i < PPED) {
      px = (double)pos[n * 2];
      py = (double)pos[n * 2 + 1];
      sx[i] = px;
      sy[i] = py;
      xb = (double)bpos[n * 2];
      yb = (double)bpos[n * 2 + 1];
    }
    __syncthreads();
    unsigned long long mw = 0ull;
    if (i < PPED) {
      double xr = px - xb, yr = py - yb;
      double safe = (xr == 0.0) ? 1.0 : fabs(xr);
      double at = atan(fabs(yr) / safe);
      const double r90 = M_PI / 2.0, r180 = M_PI, r270 = 3.0 * M_PI / 2.0;
      double ang;
      if (xr > 0.0 && yr > 0.0) ang = at + r270;
      else if (xr < 0.0 && yr > 0.0) ang = r90 - at;
      else if (xr < 0.0 && yr < 0.0) ang = r90 + at;
      else if (xr > 0.0 && yr < 0.0) ang = r270 - at;
      else if (xr == 0.0 && yr > 0.0) ang = 0.0;
      else if (xr == 0.0 && yr < 0.0) ang = r180;
      else if (yr == 0.0 && xr > 0.0) ang = r270;
      else if (yr == 0.0 && xr < 0.0) ang = r90;
      else ang = 0.0;
      double cd = cos(ang), sd = sin(ang);
      const double cc2 = 2.0 / cos(60.0 * M_PI / 180.0);
      const double bb = sin(60.0 * M_PI / 180.0) * cc2;  // 2*sqrt(3)
      for (int j = 0; j < PPED; ++j) {
        if (j == i) continue;
        double dx = sx[j] - px, dy = sy[j] - py;
        double xt = cd * dx - sd * dy;
        double yt = sd * dx + cd * dy;
        double res = (yt >= 0.0) ? (xt * xt + yt * yt / 4.0) : (xt * xt + yt * yt);
        bool egg = (res <= 1.0);
        double c1 = 2.0 * xt + bb * yt;
        double c2 = 2.0 * xt - bb * yt;
        bool cone = (c1 > 0.0 && c2 < 0.0) || (c1 == 0.0) || (c2 == 0.0);
        if (egg && (yt >= 0.0) && cone) mw |= (1ull << j);
      }
      mw_sh[i] = mw;
      cnt_sh[i] = __popcll(mw);
    }
    __syncthreads();
    if (tid == 0) {
      int run = 0;
      for (int j = 0; j < PPED; ++j) {
        pref_sh[j] = run;
        run += cnt_sh[j];
      }
      unsigned int tot = (unsigned int)((run > PPS) ? PPS : run);
      ((unsigned int*)((char*)ws + SCNT_OFF))[scene] = tot;
    }
    __syncthreads();
    if (i < PPED) {
      int c = cnt_sh[i];
      int basep = pref_sh[i];
      int lim = PPS - basep;
      if (lim < 0) lim = 0;
      if (lim > c) lim = c;
      unsigned int* pairs = (unsigned int*)((char*)ws + PAIR_OFF) + scene * PPS;
      unsigned long long rem = mw;
      unsigned int hi = ((unsigned int)n) << 16;
      for (int q = 0; q < lim; ++q) {
        int j = __builtin_ctzll(rem);
        rem &= rem - 1;
        pairs[basep + q] = hi | (unsigned int)(scene * PPED + j);
      }
    }
  } else if (b < 544) {
    // ---- cat init: mx=0, mn=+inf ----
    float inf = __uint_as_float(0x7f800000u);
    float4 iv = make_float4(inf, inf, inf, inf);
    float4 zv = make_float4(0.f, 0.f, 0.f, 0.f);
    float4* cat4 = (float4*)(ws + CATF);
    int t = (b - 288) * 256 + tid;
#pragma unroll
    for (int s = 0; s < 4; ++s) {
      int f4 = t + s * 65536;
      int col = (f4 * 4) & 511;
      cat4[f4] = (col & 256) ? iv : zv;
    }
  } else if (b < 546) {
    // ---- coeff fold (for kC's staging) ----
    int m = (b - 544) * 256 + tid;
    float a0 = 0.f, a1 = 0.f, b0 = 0.f, b1 = 0.f, cs = 0.f, cv = 0.f;
    for (int e = 0; e < EE; ++e) {
      float w1 = Wm1[e * MHID + m];
      float w2 = Wm1[(EE + e) * MHID + m];
      a0 = fmaf(Ws[e], w1, a0);
      a1 = fmaf(Ws[EE + e], w1, a1);
      b0 = fmaf(Wv[e], w2, b0);
      b1 = fmaf(Wv[EE + e], w2, b1);
      cs = fmaf(bs[e], w1, cs);
      cv = fmaf(bv[e], w2, cv);
    }
    ws[m] = a0;
    ws[MHID + m] = a1;
    ws[2 * MHID + m] = b0;
    ws[3 * MHID + m] = b1;
    ws[4 * MHID + m] = bm1[m] + cs + cv;
  } else {
    // ---- transpose 16-col slab of Wm2 or Wp -> bf16 [256][512] ----
    unsigned short* Tsh = (unsigned short*)smem;
    const float* src = (b < 562) ? Wm2 : Wp;
    unsigned short* dst = (unsigned short*)((char*)ws + ((b < 562) ? W2T_OFF : WPT_OFF));
    int c0 = ((b < 562) ? (b - 546) : (b - 562)) * 16;
#pragma unroll 4
    for (int it = 0; it < 32; ++it) {
      int k = it * 16 + (tid >> 4);
      int c = tid & 15;
      Tsh[c * MHID + k] = f2bf(src[(size_t)k * DD + c0 + c]);
    }
    __syncthreads();
    unsigned int* dst32 = (unsigned int*)dst;
#pragma unroll 4
    for (int it = 0; it < 16; ++it) {
      int flat = it * 256 + tid;
      int c = flat >> 8;
      int ku = flat & 255;
      unsigned int lo = Tsh[c * MHID + 2 * ku];
      unsigned int hi = Tsh[c * MHID + 2 * ku + 1];
      dst32[(size_t)(c0 + c) * (MHID / 2) + ku] = lo | (hi << 16);
    }
  }
}

// ============ kC: per-scene pair tiles — MFMA layer2 + run-scan pooling ==========
__global__ __launch_bounds__(256) void kC(const float* __restrict__ ws,
                                          const float* __restrict__ pos,
                                          const float* __restrict__ vel,
                                          const float* __restrict__ bm2,
                                          float* __restrict__ cat) {
  int s = blockIdx.x >> 6, t = blockIdx.x & (MAXT - 1);
  int np = (int)((const unsigned int*)((const char*)ws + SCNT_OFF))[s];
  int t0 = t * TILE;
  if (t0 >= np) return;
  __shared__ __align__(16) float smem[4096];  // A(bf16 16x512 swz) then H2[16][256]
  __shared__ int si[TILE], sjj[TILE];
  __shared__ float spv[TILE][4];
  unsigned short* Ash = (unsigned short*)smem;
  const unsigned short* u16 = (const unsigned short*)((const char*)ws + U16_OFF);
  const short* w2t = (const short*)((const char*)ws + W2T_OFF);
  const unsigned int* pairs = (const unsigned int*)((const char*)ws + PAIR_OFF) + s * PPS;
  int tid = threadIdx.x;
  if (tid < TILE) {
    int p = t0 + tid;
    unsigned int pk = (p < np) ? pairs[p] : pairs[t0];
    int ii = (int)(pk >> 16), jj = (int)(pk & 0xFFFFu);
    si[tid] = ii;
    sjj[tid] = jj;
    spv[tid][0] = pos[jj * 2] - pos[ii * 2];
    spv[tid][1] = pos[jj * 2 + 1] - pos[ii * 2 + 1];
    spv[tid][2] = vel[jj * 2] - vel[ii * 2];
    spv[tid][3] = vel[jj * 2 + 1] - vel[ii * 2 + 1];
  }
  __syncthreads();
  // ---- stage A: h1 = relu(U_hid[j] + dp·A + dv·B + cvec) -> bf16 swizzled ----
  {
    int pr = tid & 15, seg = tid >> 4;
    int jj = sjj[pr];
    float dpx = spv[pr][0], dpy = spv[pr][1], dvx = spv[pr][2], dvy = spv[pr][3];
    const unsigned short* Up = u16 + (size_t)jj * MHID + seg * 32;
    int swz = (pr & 7) << 3;
#pragma unroll
    for (int q = 0; q < 4; ++q) {
      int k0 = seg * 32 + q * 8;
      uint4 uv = *(const uint4*)(Up + q * 8);
      float4 c0a = *(const float4*)(ws + k0);
      float4 c0b = *(const float4*)(ws + k0 + 4);
      float4 c1a = *(const float4*)(ws + MHID + k0);
      float4 c1b = *(const float4*)(ws + MHID + k0 + 4);
      float4 c2a = *(const float4*)(ws + 2 * MHID + k0);
      float4 c2b = *(const float4*)(ws + 2 * MHID + k0 + 4);
      float4 c3a = *(const float4*)(ws + 3 * MHID + k0);
      float4 c3b = *(const float4*)(ws + 3 * MHID + k0 + 4);
      float4 c4a = *(const float4*)(ws + 4 * MHID + k0);
      float4 c4b = *(const float4*)(ws + 4 * MHID + k0 + 4);
      float u0 = __half2float(__ushort_as_half((unsigned short)(uv.x & 0xffff)));
      float u1 = __half2float(__ushort_as_half((unsigned short)(uv.x >> 16)));
      float u2 = __half2float(__ushort_as_half((unsigned short)(uv.y & 0xffff)));
      float u3 = __half2float(__ushort_as_half((unsigned short)(uv.y >> 16)));
      float u4 = __half2float(__ushort_as_half((unsigned short)(uv.z & 0xffff)));
      float u5 = __half2float(__ushort_as_half((unsigned short)(uv.z >> 16)));
      float u6 = __half2float(__ushort_as_half((unsigned short)(uv.w & 0xffff)));
      float u7 = __half2float(__ushort_as_half((unsigned short)(uv.w >> 16)));
      unsigned int h0 =
          f2bf(fmaxf(u0 + dpx * c0a.x + dpy * c1a.x + dvx * c2a.x + dvy * c3a.x + c4a.x, 0.f));
      unsigned int h1 =
          f2bf(fmaxf(u1 + dpx * c0a.y + dpy * c1a.y + dvx * c2a.y + dvy * c3a.y + c4a.y, 0.f));
      unsigned int h2 =
          f2bf(fmaxf(u2 + dpx * c0a.z + dpy * c1a.z + dvx * c2a.z + dvy * c3a.z + c4a.z, 0.f));
      unsigned int h3 =
          f2bf(fmaxf(u3 + dpx * c0a.w + dpy * c1a.w + dvx * c2a.w + dvy * c3a.w + c4a.w, 0.f));
      unsigned int h4 =
          f2bf(fmaxf(u4 + dpx * c0b.x + dpy * c1b.x + dvx * c2b.x + dvy * c3b.x + c4b.x, 0.f));
      unsigned int h5 =
          f2bf(fmaxf(u5 + dpx * c0b.y + dpy * c1b.y + dvx * c2b.y + dvy * c3b.y + c4b.y, 0.f));
      unsigned int h6 =
          f2bf(fmaxf(u6 + dpx * c0b.z + dpy * c1b.z + dvx * c2b.z + dvy * c3b.z + c4b.z, 0.f));
      unsigned int h7 =
          f2bf(fmaxf(u7 + dpx * c0b.w + dpy * c1b.w + dvx * c2b.w + dvy * c3b.w + c4b.w, 0.f));
      uint4 pk4;
      pk4.x = h0 | (h1 << 16);
      pk4.y = h2 | (h3 << 16);
      pk4.z = h4 | (h5 << 16);
      pk4.w = h6 | (h7 << 16);
      *(uint4*)(Ash + (((pr * MHID + k0)) ^ swz)) = pk4;
    }
  }
  __syncthreads();
  int w = tid >> 6, l = tid & 63;
  f32x4 acc0 = {0.f, 0.f, 0.f, 0.f}, acc1 = {0.f, 0.f, 0.f, 0.f};
  f32x4 acc2 = {0.f, 0.f, 0.f, 0.f}, acc3 = {0.f, 0.f, 0.f, 0.f};
  int arow = l & 15, agrp = l >> 4;
  int aswz = (arow & 7) << 3;
#pragma unroll 4
  for (int ks = 0; ks < 16; ++ks) {
    short8 a = *(const short8*)(Ash + ((arow * MHID + ks * 32 + agrp * 8) ^ aswz));
    const short* bbase = w2t + (size_t)(w * 4 * 16 + (l & 15)) * MHID + ks * 32 + agrp * 8;
    short8 b0 = *(const short8*)(bbase);
    short8 b1 = *(const short8*)(bbase + 16 * MHID);
    short8 b2 = *(const short8*)(bbase + 32 * MHID);
    short8 b3 = *(const short8*)(bbase + 48 * MHID);
    acc0 = __builtin_amdgcn_mfma_f32_16x16x32_bf16(a, b0, acc0, 0, 0, 0);
    acc1 = __builtin_amdgcn_mfma_f32_16x16x32_bf16(a, b1, acc1, 0, 0, 0);
    acc2 = __builtin_amdgcn_mfma_f32_16x16x32_bf16(a, b2, acc2, 0, 0, 0);
    acc3 = __builtin_amdgcn_mfma_f32_16x16x32_bf16(a, b3, acc3, 0, 0, 0);
  }
  __syncthreads();
  {
#pragma unroll
    for (int t2 = 0; t2 < 4; ++t2) {
      int col = (w * 4 + t2) * 16 + (l & 15);
      float bias = bm2[col];
      f32x4 av = (t2 == 0) ? acc0 : (t2 == 1) ? acc1 : (t2 == 2) ? acc2 : acc3;
#pragma unroll
      for (int r = 0; r < 4; ++r) {
        int row = (l >> 4) * 4 + r;
        smem[row * DD + col] = fmaxf(av[r] + bias, 0.f);
      }
    }
  }
  __syncthreads();
  int col = tid;
  int lastv = np - t0;
  if (lastv > TILE) lastv = TILE;
  float rmx = 0.f, rmn = 0.f;
  int cur = -1, rs = 0;
  for (int r = 0; r < lastv; ++r) {
    int ii = si[r];
    float v = smem[r * DD + col];
    if (ii != cur) {
      if (cur >= 0) {
        bool shared_run = (rs == 0 && t0 > 0);
        float* mp = cat + (size_t)cur * 2 * DD + col;
        if (shared_run) {
          atomicMax((unsigned int*)mp, __float_as_uint(rmx));
          atomicMin((unsigned int*)(mp + DD), __float_as_uint(rmn));
        } else {
          mp[0] = rmx;
          mp[DD] = rmn;
        }
      }
      cur = ii;
      rs = r;
      rmx = v;
      rmn = v;
    } else {
      rmx = fmaxf(rmx, v);
      rmn = fminf(rmn, v);
    }
  }
  if (cur >= 0) {
    bool shared_run = (rs == 0 && t0 > 0) || ((lastv == TILE) && (t0 + TILE) < np);
    float* mp = cat + (size_t)cur * 2 * DD + col;
    if (shared_run) {
      atomicMax((unsigned int*)mp, __float_as_uint(rmx));
      atomicMin((unsigned int*)(mp + DD), __float_as_uint(rmn));
    } else {
      mp[0] = rmx;
      mp[DD] = rmn;
    }
  }
}

// ============ kD: out = relu(cat @ Wp + bp) via MFMA ============
__global__ __launch_bounds__(256) void kD(const float* __restrict__ ws,
                                          const float* __restrict__ bp,
                                          float* __restrict__ out) {
  const float* cat = ws + CATF;
  const short* wpt = (const short*)((const char*)ws + WPT_OFF);
  int m0 = blockIdx.x * 16;
  int tid = threadIdx.x;
  int w = tid >> 6, l = tid & 63;
  int arow = m0 + (l & 15), agrp = l >> 4;
  f32x4 acc0 = {0.f, 0.f, 0.f, 0.f}, acc1 = {0.f, 0.f, 0.f, 0.f};
  f32x4 acc2 = {0.f, 0.f, 0.f, 0.f}, acc3 = {0.f, 0.f, 0.f, 0.f};
#pragma unroll 4
  for (int ks = 0; ks < 16; ++ks) {
    const float* ap = cat + (size_t)arow * MHID + ks * 32 + agrp * 8;
    float4 fa = *(const float4*)(ap);
    float4 fb = *(const float4*)(ap + 4);
    unsigned int e0 = __float_as_uint(fa.x), e1 = __float_as_uint(fa.y);
    unsigned int e2 = __float_as_uint(fa.z), e3 = __float_as_uint(fa.w);
    unsigned int e4 = __float_as_uint(fb.x), e5 = __float_as_uint(fb.y);
    unsigned int e6 = __float_as_uint(fb.z), e7 = __float_as_uint(fb.w);
    unsigned int h0 = (e0 == 0x7f800000u) ? 0u : (unsigned int)f2bf(fa.x);
    unsigned int h1 = (e1 == 0x7f800000u) ? 0u : (unsigned int)f2bf(fa.y);
    unsigned int h2 = (e2 == 0x7f800000u) ? 0u : (unsigned int)f2bf(fa.z);
    unsigned int h3 = (e3 == 0x7f800000u) ? 0u : (unsigned int)f2bf(fa.w);
    unsigned int h4 = (e4 == 0x7f800000u) ? 0u : (unsigned int)f2bf(fb.x);
    unsigned int h5 = (e5 == 0x7f800000u) ? 0u : (unsigned int)f2bf(fb.y);
    unsigned int h6 = (e6 == 0x7f800000u) ? 0u : (unsigned int)f2bf(fb.z);
    unsigned int h7 = (e7 == 0x7f800000u) ? 0u : (unsigned int)f2bf(fb.w);
    union {
      unsigned int u[4];
      short8 s;
    } av;
    av.u[0] = h0 | (h1 << 16);
    av.u[1] = h2 | (h3 << 16);
    av.u[2] = h4 | (h5 << 16);
    av.u[3] = h6 | (h7 << 16);
    const short* bbase = wpt + (size_t)(w * 64 + (l & 15)) * MHID + ks * 32 + agrp * 8;
    short8 b0 = *(const short8*)(bbase);
    short8 b1 = *(const short8*)(bbase + 16 * MHID);
    short8 b2 = *(const short8*)(bbase + 32 * MHID);
    short8 b3 = *(const short8*)(bbase + 48 * MHID);
    acc0 = __builtin_amdgcn_mfma_f32_16x16x32_bf16(av.s, b0, acc0, 0, 0, 0);
    acc1 = __builtin_amdgcn_mfma_f32_16x16x32_bf16(av.s, b1, acc1, 0, 0, 0);
    acc2 = __builtin_amdgcn_mfma_f32_16x16x32_bf16(av.s, b2, acc2, 0, 0, 0);
    acc3 = __builtin_amdgcn_mfma_f32_16x16x32_bf16(av.s, b3, acc3, 0, 0, 0);
  }
#pragma unroll
  for (int t = 0; t < 4; ++t) {
    int col = (w * 4 + t) * 16 + (l & 15);
    float bias = bp[col];
    f32x4 av = (t == 0) ? acc0 : (t == 1) ? acc1 : (t == 2) ? acc2 : acc3;
#pragma unroll
    for (int r = 0; r < 4; ++r) {
      int row = m0 + (l >> 4) * 4 + r;
      out[(size_t)row * DD + col] = fmaxf(av[r] + bias, 0.f);
    }
  }
}

extern "C" void kernel_launch(void* const* d_in, const int* in_sizes, int n_in,
                              void* d_out, int out_size, void* d_ws, size_t ws_size,
                              hipStream_t stream) {
  const float* hstates = (const float*)d_in[0];
  const float* pos = (const float*)d_in[2];
  const float* vel = (const float*)d_in[3];
  const float* bpos = (const float*)d_in[4];
  const float* Ws = (const float*)d_in[5];
  const float* bs = (const float*)d_in[6];
  const float* Wv = (const float*)d_in[7];
  const float* bv = (const float*)d_in[8];
  const float* Wm1 = (const float*)d_in[9];
  const float* bm1 = (const float*)d_in[10];
  const float* Wm2 = (const float*)d_in[11];
  const float* bm2 = (const float*)d_in[12];
  const float* Wp = (const float*)d_in[13];
  const float* bp = (const float*)d_in[14];
  float* ws = (float*)d_ws;
  float* out = (float*)d_out;

  hipLaunchKernelGGL(kB, dim3(578), dim3(256), 0, stream, hstates, pos, vel, bpos, Ws, bs,
                     Wv, bv, Wm1, bm1, Wm2, Wp, ws);
  hipLaunchKernelGGL(kC, dim3(NSC * MAXT), dim3(256), 0, stream, ws, pos, vel, bm2,
                     ws + CATF);
  hipLaunchKernelGGL(kD, dim3(NTOT / 16), dim3(256), 0, stream, ws, bp, out);
}